// Round 4
// baseline (146.644 us; speedup 1.0000x reference)
//
#include <hip/hip_runtime.h>
#include <hip/hip_cooperative_groups.h>

namespace cg = cooperative_groups;

#define B 8
#define H 512
#define W 512
#define HW (H * W)      // 262144 = 2^18
#define BHW (B * H * W) // 2097152

// d_ws layout:
//   [0   ..127]  double sums[16]   (gt: b0..7, seg: b8..15)
//   [128 ..191]  uint   maxbuf[16]
//   [256 ..]     u16 ud_gt[BHW], u16 ud_seg[BHW]   (4 MiB each)
//
// Single cooperative kernel, 256 blocks x 512 threads (1 block/CU):
//   Phase V: vertical 1D distance (u16, clamp 65535 -- exact vs reference's
//            1e6+h prefix except for an all-foreground column, P~2^-512).
//            Thread = (column, 32-row segment), mask packed in a u32,
//            distances via clz/ffs, cross-segment fixup via LDS + 1 barrier.
//            Block 0 also zeroes the sums/maxbuf header (pre-barrier).
//   grid.sync()
//   Phase H: per-row parabola min (exact early-exit: skipped candidates
//            s[k]+rr >= rr >= best, bitwise == full scan) for both masks,
//            fused loss accumulation; wave = 2 rows; block atomics.
//   grid.sync()
//   Block 0 finalizes the scalar via atomic read-backs (XCD-safe).
__global__ __launch_bounds__(512) void fused_kernel(
    const float* __restrict__ output, const int* __restrict__ target,
    unsigned short* __restrict__ ud_gt, unsigned short* __restrict__ ud_seg,
    double* __restrict__ sums, unsigned int* __restrict__ maxbuf,
    float* __restrict__ out) {
  const int bx = blockIdx.x;
  const int tid = threadIdx.x;
  cg::grid_group grid = cg::this_grid();

  __shared__ int sLast[16][32];
  __shared__ int sFirst[16][32];
  __shared__ float sg[8][W];
  __shared__ float ss[8][W];
  __shared__ double bsg[8], bss[8];
  __shared__ float bmg[8], bms[8];

  // ---------------- Phase V ----------------
  if (bx == 0 && tid < 48) ((unsigned int*)sums)[tid] = 0u; // 192B header

  {
    const int strip = bx & 15;
    const int b = (bx >> 4) & 7;
    const int maskSel = bx >> 7;
    const int c = tid & 31;          // col within strip
    const int col = strip * 32 + c;  // 0..511
    const int seg = tid >> 5;        // 0..15
    const int h0 = seg * 32;

    const int* tsrc = target + (size_t)b * HW + col;
    const float* osrc = output + (size_t)(2 * b + 1) * HW + col;
    unsigned short* dst = (maskSel ? ud_seg : ud_gt) + (size_t)b * HW + col;

    // bit i set <=> pixel at row h0+i is background (False)
    unsigned int bits = 0;
    if (maskSel == 0) {
#pragma unroll
      for (int i = 0; i < 32; ++i) {
        if (!(tsrc[(h0 + i) * W] > 0)) bits |= 1u << i;
      }
    } else {
#pragma unroll
      for (int i = 0; i < 32; ++i) {
        if (!(osrc[(h0 + i) * W] > 0.5f)) bits |= 1u << i;
      }
    }

    sLast[seg][c] = bits ? (h0 + 31 - __clz(bits)) : -1000001;
    sFirst[seg][c] = bits ? (h0 + __ffs(bits) - 1) : 2000000;
    __syncthreads();

    int inLF = -1000001; // no False above: h - inLF > 65535 -> clamps
    int inNF = 2000000;  // no False below: nf - h > 65535 -> clamps
#pragma unroll
    for (int s = 0; s < 16; ++s) {
      int sl = sLast[s][c];
      int sf = sFirst[s][c];
      if (s < seg) inLF = max(inLF, sl);
      if (s > seg) inNF = min(inNF, sf);
    }

#pragma unroll
    for (int i = 0; i < 32; ++i) {
      const int h = h0 + i;
      unsigned int below = bits & (0xFFFFFFFFu >> (31 - i));
      unsigned int above = bits >> i;
      int lf = below ? (h0 + 31 - __clz(below)) : inLF;
      int nf = above ? (h + __ffs(above) - 1) : inNF;
      int v = min(min(h - lf, nf - h), 65535);
      dst[h * W] = (unsigned short)v;
    }
  }

  grid.sync();

  // ---------------- Phase H ----------------
  {
    const int lane = tid & 63;
    const int wave = tid >> 6; // 0..7
    const int R0 = bx * 16;    // 16 rows per block, same batch
    const int b = R0 >> 9;

    double sgd = 0.0, ssd = 0.0;
    float mg = 0.f, ms = 0.f;

    float* gS = sg[wave];
    float* sS = ss[wave];

#pragma unroll
    for (int rep = 0; rep < 2; ++rep) {
      const int rb = R0 + wave + rep * 8; // global row
      const int h = rb & (H - 1);

      // one uint4 per lane = 8 u16 -> whole 512-wide row per wave
      uint4 gu = ((const uint4*)(ud_gt + (size_t)rb * W))[lane];
      uint4 su = ((const uint4*)(ud_seg + (size_t)rb * W))[lane];
      auto sq2 = [](unsigned int u, float& a, float& bq) {
        float x = (float)(u & 0xffffu);
        float y = (float)(u >> 16);
        a = x * x;
        bq = y * y;
      };
      float4 lo, hi;
      sq2(gu.x, lo.x, lo.y); sq2(gu.y, lo.z, lo.w);
      sq2(gu.z, hi.x, hi.y); sq2(gu.w, hi.z, hi.w);
      ((float4*)gS)[2 * lane] = lo;
      ((float4*)gS)[2 * lane + 1] = hi;
      sq2(su.x, lo.x, lo.y); sq2(su.y, lo.z, lo.w);
      sq2(su.z, hi.x, hi.y); sq2(su.w, hi.z, hi.w);
      ((float4*)sS)[2 * lane] = lo;
      ((float4*)sS)[2 * lane + 1] = hi;
      // wave-private LDS slab: no barrier needed (compiler waits lgkmcnt)

      float bg[8], bs[8];
      float m = 0.f;
#pragma unroll
      for (int i = 0; i < 8; ++i) {
        int j = lane + 64 * i;
        bg[i] = gS[j];
        bs[i] = sS[j];
        m = fmaxf(m, fmaxf(bg[i], bs[i]));
      }
      for (int r = 1; r < W; ++r) {
        float rr = (float)(r * r);
        if (rr >= m) break;
        m = 0.f;
#pragma unroll
        for (int i = 0; i < 8; ++i) {
          int j = lane + 64 * i;
          int kl = j - r, kr = j + r;
          float gl = (kl >= 0) ? gS[kl] : 4e12f;
          float gr = (kr < W) ? gS[kr] : 4e12f;
          float sl = (kl >= 0) ? sS[kl] : 4e12f;
          float sr = (kr < W) ? sS[kr] : 4e12f;
          bg[i] = fminf(bg[i], fminf(gl + rr, gr + rr));
          bs[i] = fminf(bs[i], fminf(sl + rr, sr + rr));
          m = fmaxf(m, fmaxf(bg[i], bs[i]));
        }
      }

      const float* oRow = output + (size_t)(2 * b + 1) * HW + (size_t)h * W;
      const int* tRow = target + (size_t)b * HW + (size_t)h * W;
      float sgf = 0.f, ssf = 0.f;
#pragma unroll
      for (int i = 0; i < 8; ++i) {
        int j = lane + 64 * i;
        float o = oRow[j];
        float t = (float)tRow[j];
        float dq = (o - t) * (o - t);
        sgf += dq * bg[i];
        ssf += dq * bs[i];
        mg = fmaxf(mg, bg[i]);
        ms = fmaxf(ms, bs[i]);
      }
      sgd += (double)sgf;
      ssd += (double)ssf;
    }

#pragma unroll
    for (int off = 32; off; off >>= 1) {
      sgd += __shfl_down(sgd, off);
      ssd += __shfl_down(ssd, off);
      mg = fmaxf(mg, __shfl_down(mg, off));
      ms = fmaxf(ms, __shfl_down(ms, off));
    }
    if (lane == 0) {
      bsg[wave] = sgd;
      bss[wave] = ssd;
      bmg[wave] = mg;
      bms[wave] = ms;
    }
    __syncthreads();
    if (tid == 0) {
      double tg = 0.0, ts = 0.0;
      float xg = 0.f, xs = 0.f;
#pragma unroll
      for (int wv = 0; wv < 8; ++wv) {
        tg += bsg[wv];
        ts += bss[wv];
        xg = fmaxf(xg, bmg[wv]);
        xs = fmaxf(xs, bms[wv]);
      }
      atomicAdd(&sums[b], tg);
      atomicAdd(&sums[8 + b], ts);
      atomicMax(&maxbuf[b], __float_as_uint(xg)); // vals >= 0: uint order ok
      atomicMax(&maxbuf[8 + b], __float_as_uint(xs));
    }
  }

  grid.sync();

  // ---------------- Finalize (block 0) ----------------
  if (bx == 0 && tid == 0) {
    double t = 0.0;
#pragma unroll
    for (int b = 0; b < 8; ++b) {
      // non-destructive atomic RMW read-back: coherent across XCDs
      double sgv = atomicAdd(&sums[b], 0.0);
      double ssv = atomicAdd(&sums[8 + b], 0.0);
      float xg = __uint_as_float(atomicMax(&maxbuf[b], 0u));
      float xs = __uint_as_float(atomicMax(&maxbuf[8 + b], 0u));
      t += sgv / (double)(xg > 0.f ? xg : 1.f);
      t += ssv / (double)(xs > 0.f ? xs : 1.f);
    }
    out[0] = (float)(t * (1.0 / (double)BHW));
  }
}

extern "C" void kernel_launch(void* const* d_in, const int* in_sizes, int n_in,
                              void* d_out, int out_size, void* d_ws,
                              size_t ws_size, hipStream_t stream) {
  const float* output = (const float*)d_in[0]; // [8,2,512,512] f32
  const int* target = (const int*)d_in[1];     // [8,1,512,512] i32

  double* sums = (double*)d_ws;
  unsigned int* maxbuf = (unsigned int*)((char*)d_ws + 128);
  unsigned short* ud_gt = (unsigned short*)((char*)d_ws + 256);
  unsigned short* ud_seg = ud_gt + BHW;
  float* outp = (float*)d_out;

  void* args[] = {(void*)&output, (void*)&target, (void*)&ud_gt,
                  (void*)&ud_seg, (void*)&sums,   (void*)&maxbuf,
                  (void*)&outp};
  hipLaunchCooperativeKernel((const void*)fused_kernel, dim3(256), dim3(512),
                             args, 0, stream);
}

// Round 5
// 94.846 us; speedup vs baseline: 1.5461x; 1.5461x over previous
//
#include <hip/hip_runtime.h>

#define B 8
#define H 512
#define W 512
#define HW (H * W)      // 262144 = 2^18
#define BHW (B * H * W) // 2097152

// d_ws layout:
//   [0   ..127]  double sums[16]   (gt: b0..7, seg: b8..15)
//   [128 ..191]  uint   maxbuf[16]
//   [192 ..195]  uint   counter
//   [256 ..]     u16 ud_gt[BHW], u16 ud_seg[BHW]   (4 MiB each)

// ---------------------------------------------------------------------------
// Kernel V: vertical 1D distance along H, both masks, u16 output.
// fw[h] = h - lastFalse(<=h), bw[h] = nextFalse(>=h) - h; min, clamp 65535.
// Clamp differs from the reference's 1e6+h prefix only for a column with NO
// background pixel (P ~ 2^-512 for this input), and even then 65535^2 loses
// every parabola min unless the whole image is foreground.
// Thread = (column, 32-row segment); mask packed in a u32; per-row distances
// via clz/ffs; cross-segment fixup via LDS summary + 1 barrier.
// 512 thr/block, 256 blocks (16 strips x 8 batches x 2 masks): 8 waves/CU,
// 32 independent loads/thread -- 2x the latency hiding of the 256-thr version.
// Block 0 also zeroes the 256-byte header (sums/maxbuf/counter).
// ---------------------------------------------------------------------------
__global__ __launch_bounds__(512) void vert_kernel(
    const float* __restrict__ output, const int* __restrict__ target,
    unsigned short* __restrict__ ud_gt, unsigned short* __restrict__ ud_seg,
    unsigned int* __restrict__ hdr) {
  const int tid = threadIdx.x;
  const int bx = blockIdx.x;
  if (bx == 0 && tid < 64) hdr[tid] = 0u; // zero 256B header

  const int strip = bx & 15;
  const int b = (bx >> 4) & 7;
  const int maskSel = bx >> 7;
  const int c = tid & 31;         // col within strip
  const int col = strip * 32 + c; // 0..511
  const int seg = tid >> 5;       // 0..15
  const int h0 = seg * 32;

  const int* tsrc = target + (size_t)b * HW + col;
  const float* osrc = output + (size_t)(2 * b + 1) * HW + col;
  unsigned short* dst = (maskSel ? ud_seg : ud_gt) + (size_t)b * HW + col;

  // bit i set <=> pixel at row h0+i is background (False)
  unsigned int bits = 0;
  if (maskSel == 0) {
#pragma unroll
    for (int i = 0; i < 32; ++i) {
      if (!(tsrc[(h0 + i) * W] > 0)) bits |= 1u << i;
    }
  } else {
#pragma unroll
    for (int i = 0; i < 32; ++i) {
      if (!(osrc[(h0 + i) * W] > 0.5f)) bits |= 1u << i;
    }
  }

  __shared__ int sLast[16][32];
  __shared__ int sFirst[16][32];
  sLast[seg][c] = bits ? (h0 + 31 - __clz(bits)) : -1000001;
  sFirst[seg][c] = bits ? (h0 + __ffs(bits) - 1) : 2000000;
  __syncthreads();

  int inLF = -1000001; // no False above: h - inLF > 65535 -> clamps
  int inNF = 2000000;  // no False below: nf - h > 65535 -> clamps
#pragma unroll
  for (int s = 0; s < 16; ++s) {
    int sl = sLast[s][c];
    int sf = sFirst[s][c];
    if (s < seg) inLF = max(inLF, sl);
    if (s > seg) inNF = min(inNF, sf);
  }

#pragma unroll
  for (int i = 0; i < 32; ++i) {
    const int h = h0 + i;
    unsigned int below = bits & (0xFFFFFFFFu >> (31 - i));
    unsigned int above = bits >> i;
    int lf = below ? (h0 + 31 - __clz(below)) : inLF;
    int nf = above ? (h + __ffs(above) - 1) : inNF;
    int v = min(min(h - lf, nf - h), 65535);
    dst[h * W] = (unsigned short)v;
  }
}

// ---------------------------------------------------------------------------
// Kernel H: per-row parabola min (exact early-exit) for both masks + fused
// loss accumulation + last-block finalize. One wave per row, 8 cols/lane.
// Early exit is bitwise-exact: skipped candidates s[k]+rr >= rr >= best.
// 512 blocks x 8 waves = 16 waves/CU.
// ---------------------------------------------------------------------------
__global__ __launch_bounds__(512) void horiz_kernel(
    const float* __restrict__ output, const int* __restrict__ target,
    const unsigned short* __restrict__ ud_gt,
    const unsigned short* __restrict__ ud_seg, double* __restrict__ sums,
    unsigned int* __restrict__ maxbuf, unsigned int* __restrict__ counter,
    float* __restrict__ out) {
  const int tid = threadIdx.x;
  const int lane = tid & 63;
  const int wave = tid >> 6;            // 0..7
  const int rb = blockIdx.x * 8 + wave; // row 0..4095
  const int b = rb >> 9;
  const int h = rb & (H - 1);

  __shared__ float sg[8][W];
  __shared__ float ss[8][W];

  // one uint4 per lane = 8 u16 covers the whole 512-wide row per wave
  const unsigned short* gRow = ud_gt + (size_t)rb * W;
  const unsigned short* sRow = ud_seg + (size_t)rb * W;
  uint4 gu = ((const uint4*)gRow)[lane];
  uint4 su = ((const uint4*)sRow)[lane];

  auto sq2 = [](unsigned int u, float& a, float& bq) {
    float x = (float)(u & 0xffffu);
    float y = (float)(u >> 16);
    a = x * x;
    bq = y * y;
  };
  float4 lo, hi;
  sq2(gu.x, lo.x, lo.y); sq2(gu.y, lo.z, lo.w);
  sq2(gu.z, hi.x, hi.y); sq2(gu.w, hi.z, hi.w);
  ((float4*)sg[wave])[2 * lane] = lo;
  ((float4*)sg[wave])[2 * lane + 1] = hi;
  sq2(su.x, lo.x, lo.y); sq2(su.y, lo.z, lo.w);
  sq2(su.z, hi.x, hi.y); sq2(su.w, hi.z, hi.w);
  ((float4*)ss[wave])[2 * lane] = lo;
  ((float4*)ss[wave])[2 * lane + 1] = hi;
  __syncthreads();

  const float* g = sg[wave];
  const float* s = ss[wave];
  float bg[8], bs[8];
  float m = 0.f;
#pragma unroll
  for (int i = 0; i < 8; ++i) {
    int j = lane + 64 * i;
    bg[i] = g[j];
    bs[i] = s[j];
    m = fmaxf(m, fmaxf(bg[i], bs[i]));
  }
  for (int r = 1; r < W; ++r) {
    float rr = (float)(r * r);
    if (rr >= m) break;
    m = 0.f;
#pragma unroll
    for (int i = 0; i < 8; ++i) {
      int j = lane + 64 * i;
      int kl = j - r, kr = j + r;
      float gl = (kl >= 0) ? g[kl] : 4e12f;
      float gr = (kr < W) ? g[kr] : 4e12f;
      float sl = (kl >= 0) ? s[kl] : 4e12f;
      float sr = (kr < W) ? s[kr] : 4e12f;
      bg[i] = fminf(bg[i], fminf(gl + rr, gr + rr));
      bs[i] = fminf(bs[i], fminf(sl + rr, sr + rr));
      m = fmaxf(m, fmaxf(bg[i], bs[i]));
    }
  }

  // fused loss: dsq=(out1-gt)^2; accumulate dsq*dt2 per mask and max(dt2)
  const float* oRow = output + (size_t)(2 * b + 1) * HW + (size_t)h * W;
  const int* tRow = target + (size_t)b * HW + (size_t)h * W;
  float mg = 0.f, ms = 0.f, sgf = 0.f, ssf = 0.f;
#pragma unroll
  for (int i = 0; i < 8; ++i) {
    int j = lane + 64 * i;
    float o = oRow[j];
    float t = (float)tRow[j];
    float dq = (o - t) * (o - t);
    sgf += dq * bg[i];
    ssf += dq * bs[i];
    mg = fmaxf(mg, bg[i]);
    ms = fmaxf(ms, bs[i]);
  }
  double sgd = (double)sgf, ssd = (double)ssf;
#pragma unroll
  for (int off = 32; off; off >>= 1) {
    sgd += __shfl_down(sgd, off);
    ssd += __shfl_down(ssd, off);
    mg = fmaxf(mg, __shfl_down(mg, off));
    ms = fmaxf(ms, __shfl_down(ms, off));
  }
  __shared__ double bsg[8], bss[8];
  __shared__ float bmg[8], bms[8];
  __shared__ unsigned int lastFlag;
  if (lane == 0) {
    bsg[wave] = sgd;
    bss[wave] = ssd;
    bmg[wave] = mg;
    bms[wave] = ms;
  }
  __syncthreads();
  if (tid == 0) {
    double tg = 0.0, ts = 0.0;
    float xg = 0.f, xs = 0.f;
#pragma unroll
    for (int wv = 0; wv < 8; ++wv) {
      tg += bsg[wv];
      ts += bss[wv];
      xg = fmaxf(xg, bmg[wv]);
      xs = fmaxf(xs, bms[wv]);
    }
    atomicAdd(&sums[b], tg);
    atomicAdd(&sums[8 + b], ts);
    atomicMax(&maxbuf[b], __float_as_uint(xg)); // vals >= 0: uint order ok
    atomicMax(&maxbuf[8 + b], __float_as_uint(xs));
    __threadfence(); // release our partials before announcing
    unsigned int old = atomicAdd(counter, 1u);
    lastFlag = (old == (unsigned int)(B * H / 8 - 1)) ? 1u : 0u;
  }
  __syncthreads();

  if (lastFlag && tid < 64) {
    __threadfence(); // acquire
    double t = 0.0;
    if (tid < 8) {
      // non-destructive atomic RMW read-back: coherent across XCDs
      double sgv = atomicAdd(&sums[tid], 0.0);
      double ssv = atomicAdd(&sums[8 + tid], 0.0);
      float xg = __uint_as_float(atomicMax(&maxbuf[tid], 0u));
      float xs = __uint_as_float(atomicMax(&maxbuf[8 + tid], 0u));
      t = sgv / (double)(xg > 0.f ? xg : 1.f) +
          ssv / (double)(xs > 0.f ? xs : 1.f);
    }
    t += __shfl_down(t, 4);
    t += __shfl_down(t, 2);
    t += __shfl_down(t, 1);
    if (tid == 0) out[0] = (float)(t * (1.0 / (double)BHW));
  }
}

extern "C" void kernel_launch(void* const* d_in, const int* in_sizes, int n_in,
                              void* d_out, int out_size, void* d_ws,
                              size_t ws_size, hipStream_t stream) {
  const float* output = (const float*)d_in[0]; // [8,2,512,512] f32
  const int* target = (const int*)d_in[1];     // [8,1,512,512] i32

  double* sums = (double*)d_ws;
  unsigned int* maxbuf = (unsigned int*)((char*)d_ws + 128);
  unsigned int* counter = (unsigned int*)((char*)d_ws + 192);
  unsigned int* hdr = (unsigned int*)d_ws;
  unsigned short* ud_gt = (unsigned short*)((char*)d_ws + 256);
  unsigned short* ud_seg = ud_gt + BHW;

  vert_kernel<<<dim3(256), 512, 0, stream>>>(output, target, ud_gt, ud_seg,
                                             hdr);
  horiz_kernel<<<dim3(B * H / 8), 512, 0, stream>>>(
      output, target, ud_gt, ud_seg, sums, maxbuf, counter, (float*)d_out);
}